// Round 7
// baseline (482.182 us; speedup 1.0000x reference)
//
#include <hip/hip_runtime.h>
#include <stdint.h>

// Triangle multiplicative update (outgoing), N=512, CZ=CH=128.
// Stage A (proj_fuse v7): BARRIER-FREE / LDS-FREE. R6 showed occupancy
//   stuck at 28% with all pipes <32%: the per-tile __syncthreads coupled
//   the block's waves to the slowest stage-load. z is L3-resident, so each
//   wave now loads its own A-fragment slices (fp32, 2x float4 per frag)
//   directly from global and packs with cvt_pk — no LDS, no barriers;
//   waves stream independently and the compiler pipelines across tiles.
//   Weights VGPR-resident+pinned (64 VGPR/wave), lb(256,3) (NEVER cap
//   below pinned live set — R5's lb(256,6) spilled: 400us).
// Stage B (tri_gemm v5, unchanged): counted-vmcnt double-buffer, loads in
//   flight across raw s_barriers; c-locality XCD swizzle.

#define NDIM 512
#define CZ   128
#define CH   128
#define NPOS (NDIM * NDIM)  // 262144
#define NTILE 8             // position tiles per proj_fuse block
#define POSB  (NTILE * 32)  // 256 positions per block

typedef __attribute__((ext_vector_type(8))) __bf16 bf16x8;
typedef __attribute__((ext_vector_type(4))) float  f32x4;
typedef __attribute__((ext_vector_type(4))) unsigned int u32x4;

__device__ __forceinline__ unsigned short f2bf(float f) {
  unsigned int u = __builtin_bit_cast(unsigned int, f);
  unsigned int r = (u + 0x7fffu + ((u >> 16) & 1u)) >> 16;  // RNE
  return (unsigned short)r;
}
// v_cvt_pk_bf16_f32: dst.lo = bf16(lo), dst.hi = bf16(hi); RNE — bit-equal
// to f2bf for normal inputs. 1 VALU op per 2 elements.
__device__ __forceinline__ unsigned int cvt_pk_bf16(float lo, float hi) {
  unsigned int r;
  asm("v_cvt_pk_bf16_f32 %0, %1, %2" : "=v"(r) : "v"(lo), "v"(hi));
  return r;
}
// pack 8 consecutive fp32 (two float4) into a bf16x8 MFMA fragment
__device__ __forceinline__ bf16x8 pack8(float4 lo, float4 hi) {
  u32x4 u = {cvt_pk_bf16(lo.x, lo.y), cvt_pk_bf16(lo.z, lo.w),
             cvt_pk_bf16(hi.x, hi.y), cvt_pk_bf16(hi.z, hi.w)};
  return __builtin_bit_cast(bf16x8, u);
}

// ---------------------------------------------------------------- kernel 0
// fp32 -> bf16 weights, layout [proj][c][k], proj: 0=ag,1=ap,2=bg,3=bp.
__global__ __launch_bounds__(256) void conv_weights(
    const float* __restrict__ wag, const float* __restrict__ wap,
    const float* __restrict__ wbg, const float* __restrict__ wbp,
    unsigned short* __restrict__ wbf) {
  int idx = blockIdx.x * 256 + threadIdx.x;  // 0..65535
  int proj = idx >> 14;
  int rem  = idx & 16383;
  const float* src = (proj == 0) ? wag : (proj == 1) ? wap : (proj == 2) ? wbg : wbp;
  wbf[idx] = f2bf(src[rem]);
}

// ---------------------------------------------------------------- kernel A
// 256 threads = 4 independent waves (no LDS, no barriers). Wave w owns
// channel quarter w for pair blockIdx.y, over 8 tiles of 32 positions.
__global__ __launch_bounds__(256, 3) void proj_fuse(
    const float* __restrict__ z,            // [NPOS][CZ]
    const float* __restrict__ mask,         // [NPOS]
    const unsigned short* __restrict__ wbf, // [4][CH][CZ] bf16
    const float* __restrict__ bias_ag, const float* __restrict__ bias_ap,
    const float* __restrict__ bias_bg, const float* __restrict__ bias_bp,
    unsigned short* __restrict__ a_ws,      // [CH][NPOS] bf16
    unsigned short* __restrict__ b_ws) {
  const int t    = threadIdx.x;
  const int lane = t & 63;
  const int w    = t >> 6;          // 0..3 = channel quarter
  const int pair = blockIdx.y;      // 0=a, 1=b
  const int base = blockIdx.x * POSB;

  const int ml    = lane & 15;
  const int q     = lane >> 4;
  const int koffl = q * 8;
  const int pg = pair * 2, pp = pg + 1;

  // ---- weights: gate + lin for 32 channels -> 64 VGPR, loaded ONCE.
  bf16x8 wg[4][2], wp[4][2];
#pragma unroll
  for (int ks = 0; ks < 4; ++ks)
#pragma unroll
    for (int ni = 0; ni < 2; ++ni) {
      const int c = w * 32 + ni * 16 + ml;
      wg[ks][ni] = *(const bf16x8*)&wbf[((size_t)pg * CH + c) * CZ + ks * 32 + koffl];
      wp[ks][ni] = *(const bf16x8*)&wbf[((size_t)pp * CH + c) * CZ + ks * 32 + koffl];
    }
  // PIN: asm-defined values cannot be rematerialized -> stay in registers.
#pragma unroll
  for (int ks = 0; ks < 4; ++ks)
#pragma unroll
    for (int ni = 0; ni < 2; ++ni) {
      asm volatile("" : "+v"(wg[ks][ni]));
      asm volatile("" : "+v"(wp[ks][ni]));
    }

  // ---- biases for this lane's channels
  const float* bgp = pair ? bias_bg : bias_ag;
  const float* bpp = pair ? bias_bp : bias_ap;
  float bg[2], bp[2];
#pragma unroll
  for (int ni = 0; ni < 2; ++ni) {
    bg[ni] = bgp[w * 32 + ni * 16 + ml];
    bp[ni] = bpp[w * 32 + ni * 16 + ml];
  }
  unsigned short* plane = pair ? b_ws : a_ws;

#pragma unroll 1
  for (int tt = 0; tt < NTILE; ++tt) {
    const int m0 = base + tt * 32;
    // this lane's two z rows (fp32), k-slice origin q*8
    const float* zr0 = z + (size_t)(m0 + ml) * CZ + koffl;
    const float* zr1 = zr0 + (size_t)16 * CZ;

    // ---- MFMA: gate+lin over [32 pos][32 ch]; A-frags loaded from global
    f32x4 ag_[2][2], ap_[2][2];
#pragma unroll
    for (int mi = 0; mi < 2; ++mi)
#pragma unroll
      for (int ni = 0; ni < 2; ++ni) {
        ag_[mi][ni] = (f32x4){0.f, 0.f, 0.f, 0.f};
        ap_[mi][ni] = (f32x4){0.f, 0.f, 0.f, 0.f};
      }

#pragma unroll
    for (int ks = 0; ks < 4; ++ks) {
      const float4 a0l = *(const float4*)(zr0 + ks * 32);
      const float4 a0h = *(const float4*)(zr0 + ks * 32 + 4);
      const float4 a1l = *(const float4*)(zr1 + ks * 32);
      const float4 a1h = *(const float4*)(zr1 + ks * 32 + 4);
      const bf16x8 af0 = pack8(a0l, a0h);
      const bf16x8 af1 = pack8(a1l, a1h);
#pragma unroll
      for (int ni = 0; ni < 2; ++ni) {
        ag_[0][ni] = __builtin_amdgcn_mfma_f32_16x16x32_bf16(af0, wg[ks][ni], ag_[0][ni], 0, 0, 0);
        ag_[1][ni] = __builtin_amdgcn_mfma_f32_16x16x32_bf16(af1, wg[ks][ni], ag_[1][ni], 0, 0, 0);
        ap_[0][ni] = __builtin_amdgcn_mfma_f32_16x16x32_bf16(af0, wp[ks][ni], ap_[0][ni], 0, 0, 0);
        ap_[1][ni] = __builtin_amdgcn_mfma_f32_16x16x32_bf16(af1, wp[ks][ni], ap_[1][ni], 0, 0, 0);
      }
    }

    // ---- in-register epilogue: out = mask*sigmoid(g+bg)*(p+bp)
    // C-layout (validated): channel = ni*16+ml, pos = mi*16+q*4+r
#pragma unroll
    for (int mi = 0; mi < 2; ++mi) {
      const int pos0 = mi * 16 + q * 4;
      const float4 mv = *(const float4*)(mask + m0 + pos0);
      const float mr[4] = {mv.x, mv.y, mv.z, mv.w};
#pragma unroll
      for (int ni = 0; ni < 2; ++ni) {
        const int c = w * 32 + ni * 16 + ml;
        float v[4];
#pragma unroll
        for (int r = 0; r < 4; ++r) {
          const float g = ag_[mi][ni][r] + bg[ni];
          const float p = ap_[mi][ni][r] + bp[ni];
          const float s = __builtin_amdgcn_rcpf(1.0f + __expf(-g));
          v[r] = mr[r] * s * p;
        }
        *(uint2*)(plane + (size_t)c * NPOS + m0 + pos0) =
            make_uint2(cvt_pk_bf16(v[0], v[1]), cvt_pk_bf16(v[2], v[3]));
      }
    }
  }
}

// ---------------------------------------------------------------- kernel B
// Per-channel GEMM out[c] = A_c * B_c^T, bf16 [512][512].
// 128x128 tile, BK=64, double-buffered LDS with COUNTED vmcnt: next
// K-tile's 8 global_load_lds stay in flight across both raw s_barriers;
// only the peeled last iteration drains. c-locality XCD swizzle.
__global__ __launch_bounds__(256, 2) void tri_gemm(
    const unsigned short* __restrict__ a_ws,
    const unsigned short* __restrict__ b_ws,
    float* __restrict__ out) {
  __shared__ unsigned short sA[2][128 * 64];  // 32 KB
  __shared__ unsigned short sB[2][128 * 64];  // 32 KB

  const int t = threadIdx.x, lane = t & 63, wave = t >> 6;
  const int wm = wave >> 1, wn = wave & 1;

  const int L    = blockIdx.x;     // 0..2047
  const int xcd  = L & 7;
  const int slot = L >> 3;         // 0..255
  const int c    = xcd * 16 + (slot >> 4);
  const int tile = slot & 15;      // 16 tiles of channel c, schedule-adjacent
  const int ti   = tile >> 2, tj = tile & 3;
  const int i0 = ti * 128, j0 = tj * 128;

  const unsigned short* Ap = a_ws + (size_t)c * NPOS + (size_t)i0 * NDIM;
  const unsigned short* Bp = b_ws + (size_t)c * NPOS + (size_t)j0 * NDIM;

  f32x4 acc[4][4];
#pragma unroll
  for (int mi = 0; mi < 4; ++mi)
#pragma unroll
    for (int ni = 0; ni < 4; ++ni) acc[mi][ni] = (f32x4){0.f, 0.f, 0.f, 0.f};

  const int srow8  = t >> 3;  // row within a 32-row staging group
  const int schunk = t & 7;   // physical 16B chunk within row
  const int mrow = wm * 64 + (lane & 15);
  const int nrow = wn * 64 + (lane & 15);

  auto STAGE = [&](int b, int kk) {  // 8 global_load_lds per thread
    const int k0 = kk * 64;  // shorts
#pragma unroll
    for (int i = 0; i < 4; ++i) {
      const int row = i * 32 + srow8;
      const int kcs = schunk ^ (row & 7);  // swizzled source chunk
      __builtin_amdgcn_global_load_lds(
          (const __attribute__((address_space(1))) unsigned int*)(Ap + (size_t)row * NDIM + k0 + kcs * 8),
          (__attribute__((address_space(3))) unsigned int*)&sA[b][(i * 256 + t) * 8], 16, 0, 0);
      __builtin_amdgcn_global_load_lds(
          (const __attribute__((address_space(1))) unsigned int*)(Bp + (size_t)row * NDIM + k0 + kcs * 8),
          (__attribute__((address_space(3))) unsigned int*)&sB[b][(i * 256 + t) * 8], 16, 0, 0);
    }
  };

  auto COMPUTE = [&](int cur) {
#pragma unroll
    for (int ksub = 0; ksub < 2; ++ksub) {
      const int kc = ksub * 4 + (lane >> 4);  // logical 16B chunk 0..7
      bf16x8 af[4], bfr[4];
#pragma unroll
      for (int mi = 0; mi < 4; ++mi) {
        const int r = mrow + mi * 16;
        af[mi] = *(const bf16x8*)&sA[cur][r * 64 + ((kc ^ (r & 7)) << 3)];
      }
#pragma unroll
      for (int ni = 0; ni < 4; ++ni) {
        const int r = nrow + ni * 16;
        bfr[ni] = *(const bf16x8*)&sB[cur][r * 64 + ((kc ^ (r & 7)) << 3)];
      }
#pragma unroll
      for (int mi = 0; mi < 4; ++mi)
#pragma unroll
        for (int ni = 0; ni < 4; ++ni)
          acc[mi][ni] = __builtin_amdgcn_mfma_f32_16x16x32_bf16(af[mi], bfr[ni], acc[mi][ni], 0, 0, 0);
    }
  };

  STAGE(0, 0);  // 8 loads in flight

#pragma unroll 1
  for (int kk = 0; kk < 7; ++kk) {
    const int cur = kk & 1;
    STAGE(cur ^ 1, kk + 1);                       // +8 loads (16 in flight)
    asm volatile("s_waitcnt vmcnt(8)" ::: "memory");  // kk's 8 complete
    __builtin_amdgcn_s_barrier();                 // buf[cur] visible to all
    COMPUTE(cur);
    __builtin_amdgcn_s_barrier();                 // all done reading buf[cur]
  }
  // peeled last K-step: drain remaining loads
  asm volatile("s_waitcnt vmcnt(0)" ::: "memory");
  __builtin_amdgcn_s_barrier();
  COMPUTE(1);

  float* O = out + (size_t)c * NPOS + (size_t)i0 * NDIM + j0;
#pragma unroll
  for (int mi = 0; mi < 4; ++mi)
#pragma unroll
    for (int r = 0; r < 4; ++r) {
      const int m = wm * 64 + mi * 16 + (lane >> 4) * 4 + r;
#pragma unroll
      for (int ni = 0; ni < 4; ++ni) {
        const int n = wn * 64 + ni * 16 + (lane & 15);
        O[(size_t)m * NDIM + n] = acc[mi][ni][r];
      }
    }
}

// ---------------------------------------------------------------- launcher
extern "C" void kernel_launch(void* const* d_in, const int* in_sizes, int n_in,
                              void* d_out, int out_size, void* d_ws, size_t ws_size,
                              hipStream_t stream) {
  const float* z    = (const float*)d_in[0];
  const float* mask = (const float*)d_in[1];
  const float* wag  = (const float*)d_in[2];
  const float* bag  = (const float*)d_in[3];
  const float* wap  = (const float*)d_in[4];
  const float* bap  = (const float*)d_in[5];
  const float* wbg  = (const float*)d_in[6];
  const float* bbg  = (const float*)d_in[7];
  const float* wbp  = (const float*)d_in[8];
  const float* bbp  = (const float*)d_in[9];
  float* out = (float*)d_out;

  unsigned short* wbf  = (unsigned short*)d_ws;
  unsigned short* a_ws = (unsigned short*)((char*)d_ws + 131072);
  unsigned short* b_ws = (unsigned short*)((char*)d_ws + 131072 + (size_t)CH * NPOS * 2);

  conv_weights<<<dim3(256), dim3(256), 0, stream>>>(wag, wap, wbg, wbp, wbf);
  proj_fuse<<<dim3(NPOS / POSB, 2), dim3(256), 0, stream>>>(
      z, mask, wbf, bag, bap, bbg, bbp, a_ws, b_ws);
  tri_gemm<<<dim3(2048), dim3(256), 0, stream>>>(a_ws, b_ws, out);
}

// Round 8
// 362.406 us; speedup vs baseline: 1.3305x; 1.3305x over previous
//
#include <hip/hip_runtime.h>
#include <stdint.h>

// Triangle multiplicative update (outgoing), N=512, CZ=CH=128.
// Stage A (proj_fuse v6, reverted-to): LDS-staged z (coalesced 256-thread
//   staging is load-bearing: v7's per-lane global fragment loads shattered
//   coalescing, 235us). Weights VGPR-resident+pinned (64 VGPR), lb(256,3)
//   (NEVER cap below pinned live set: R5 spill = 400us). T14 split
//   staging, cvt_pk_bf16 packing, rcp sigmoid. NTILE=8, grid (1024,2).
// Stage B (tri_gemm v6): 256x256 tile, BK=64, 8 waves (512 thr), dbuf LDS
//   128KB (1 block/CU), counted-vmcnt pipeline (loads in flight across raw
//   s_barriers), row-XOR swizzled chunks (validated at 128²: row stride
//   64 shorts, chunk^(row&7)). Halves L2 staging traffic per FLOP and
//   doubles MFMA:ds_read vs 128². c-locality XCD swizzle: 4 tiles of
//   channel c adjacent on one XCD.

#define NDIM 512
#define CZ   128
#define CH   128
#define NPOS (NDIM * NDIM)  // 262144
#define NTILE 8             // position tiles per proj_fuse block
#define POSB  (NTILE * 32)  // 256 positions per block

typedef __attribute__((ext_vector_type(8))) __bf16 bf16x8;
typedef __attribute__((ext_vector_type(4))) float  f32x4;

__device__ __forceinline__ unsigned short f2bf(float f) {
  unsigned int u = __builtin_bit_cast(unsigned int, f);
  unsigned int r = (u + 0x7fffu + ((u >> 16) & 1u)) >> 16;  // RNE
  return (unsigned short)r;
}
// v_cvt_pk_bf16_f32: dst.lo = bf16(lo), dst.hi = bf16(hi); RNE — bit-equal
// to f2bf for normal inputs. 1 VALU op per 2 elements.
__device__ __forceinline__ unsigned int cvt_pk_bf16(float lo, float hi) {
  unsigned int r;
  asm("v_cvt_pk_bf16_f32 %0, %1, %2" : "=v"(r) : "v"(lo), "v"(hi));
  return r;
}

// ---------------------------------------------------------------- kernel 0
// fp32 -> bf16 weights, layout [proj][c][k], proj: 0=ag,1=ap,2=bg,3=bp.
__global__ __launch_bounds__(256) void conv_weights(
    const float* __restrict__ wag, const float* __restrict__ wap,
    const float* __restrict__ wbg, const float* __restrict__ wbp,
    unsigned short* __restrict__ wbf) {
  int idx = blockIdx.x * 256 + threadIdx.x;  // 0..65535
  int proj = idx >> 14;
  int rem  = idx & 16383;
  const float* src = (proj == 0) ? wag : (proj == 1) ? wap : (proj == 2) ? wbg : wbp;
  wbf[idx] = f2bf(src[rem]);
}

// ---------------------------------------------------------------- kernel A
__global__ __launch_bounds__(256, 3) void proj_fuse(
    const float* __restrict__ z,            // [NPOS][CZ]
    const float* __restrict__ mask,         // [NPOS]
    const unsigned short* __restrict__ wbf, // [4][CH][CZ] bf16
    const float* __restrict__ bias_ag, const float* __restrict__ bias_ap,
    const float* __restrict__ bias_bg, const float* __restrict__ bias_bp,
    unsigned short* __restrict__ a_ws,      // [CH][NPOS] bf16
    unsigned short* __restrict__ b_ws) {
  __shared__ unsigned short zbuf[2][32 * 136];  // 2 x 8.7 KB, padded stride

  const int t    = threadIdx.x;
  const int lane = t & 63;
  const int w    = t >> 6;          // 0..3 = channel quarter
  const int pair = blockIdx.y;      // 0=a, 1=b
  const int base = blockIdx.x * POSB;

  const int ml    = lane & 15;
  const int q     = lane >> 4;
  const int koffl = q * 8;
  const int pg = pair * 2, pp = pg + 1;

  // ---- weights: gate + lin for 32 channels -> 64 VGPR, loaded ONCE.
  bf16x8 wg[4][2], wp[4][2];
#pragma unroll
  for (int ks = 0; ks < 4; ++ks)
#pragma unroll
    for (int ni = 0; ni < 2; ++ni) {
      const int c = w * 32 + ni * 16 + ml;
      wg[ks][ni] = *(const bf16x8*)&wbf[((size_t)pg * CH + c) * CZ + ks * 32 + koffl];
      wp[ks][ni] = *(const bf16x8*)&wbf[((size_t)pp * CH + c) * CZ + ks * 32 + koffl];
    }
  // PIN: asm-defined values cannot be rematerialized -> stay in registers.
#pragma unroll
  for (int ks = 0; ks < 4; ++ks)
#pragma unroll
    for (int ni = 0; ni < 2; ++ni) {
      asm volatile("" : "+v"(wg[ks][ni]));
      asm volatile("" : "+v"(wp[ks][ni]));
    }

  // ---- biases for this lane's channels
  const float* bgp = pair ? bias_bg : bias_ag;
  const float* bpp = pair ? bias_bp : bias_ap;
  float bg[2], bp[2];
#pragma unroll
  for (int ni = 0; ni < 2; ++ni) {
    bg[ni] = bgp[w * 32 + ni * 16 + ml];
    bp[ni] = bpp[w * 32 + ni * 16 + ml];
  }
  unsigned short* plane = pair ? b_ws : a_ws;

  // ---- T14 split staging: load early (regs), convert+write late.
  float4 stg[4];
  auto STAGE_LOAD = [&](int tt) {
    const int m0s = base + tt * 32;
#pragma unroll
    for (int it = 0; it < 4; ++it) {
      const int id  = it * 256 + t;   // 0..1023
      stg[it] = *(const float4*)(z + (size_t)(m0s + (id >> 5)) * CZ + (id & 31) * 4);
    }
  };
  auto STAGE_WRITE = [&](int b) {
#pragma unroll
    for (int it = 0; it < 4; ++it) {
      const int id = it * 256 + t;
      *(uint2*)&zbuf[b][(id >> 5) * 136 + (id & 31) * 4] =
          make_uint2(cvt_pk_bf16(stg[it].x, stg[it].y),
                     cvt_pk_bf16(stg[it].z, stg[it].w));
    }
  };

  STAGE_LOAD(0);
  STAGE_WRITE(0);
  __syncthreads();

#pragma unroll 1
  for (int tt = 0; tt < NTILE; ++tt) {
    const int m0 = base + tt * 32;
    const int cb = tt & 1;
    if (tt + 1 < NTILE) STAGE_LOAD(tt + 1);  // issue loads; hide under compute

    // ---- MFMA: gate+lin over [32 pos][32 ch]
    f32x4 ag_[2][2], ap_[2][2];
#pragma unroll
    for (int mi = 0; mi < 2; ++mi)
#pragma unroll
      for (int ni = 0; ni < 2; ++ni) {
        ag_[mi][ni] = (f32x4){0.f, 0.f, 0.f, 0.f};
        ap_[mi][ni] = (f32x4){0.f, 0.f, 0.f, 0.f};
      }

#pragma unroll
    for (int ks = 0; ks < 4; ++ks) {
      bf16x8 af0 = *(const bf16x8*)&zbuf[cb][(ml)      * 136 + ks * 32 + koffl];
      bf16x8 af1 = *(const bf16x8*)&zbuf[cb][(ml + 16) * 136 + ks * 32 + koffl];
#pragma unroll
      for (int ni = 0; ni < 2; ++ni) {
        ag_[0][ni] = __builtin_amdgcn_mfma_f32_16x16x32_bf16(af0, wg[ks][ni], ag_[0][ni], 0, 0, 0);
        ag_[1][ni] = __builtin_amdgcn_mfma_f32_16x16x32_bf16(af1, wg[ks][ni], ag_[1][ni], 0, 0, 0);
        ap_[0][ni] = __builtin_amdgcn_mfma_f32_16x16x32_bf16(af0, wp[ks][ni], ap_[0][ni], 0, 0, 0);
        ap_[1][ni] = __builtin_amdgcn_mfma_f32_16x16x32_bf16(af1, wp[ks][ni], ap_[1][ni], 0, 0, 0);
      }
    }

    // ---- in-register epilogue: out = mask*sigmoid(g+bg)*(p+bp)
    // C-layout (validated): channel = ni*16+ml, pos = mi*16+q*4+r
#pragma unroll
    for (int mi = 0; mi < 2; ++mi) {
      const int pos0 = mi * 16 + q * 4;
      const float4 mv = *(const float4*)(mask + m0 + pos0);
      const float mr[4] = {mv.x, mv.y, mv.z, mv.w};
#pragma unroll
      for (int ni = 0; ni < 2; ++ni) {
        const int c = w * 32 + ni * 16 + ml;
        float v[4];
#pragma unroll
        for (int r = 0; r < 4; ++r) {
          const float g = ag_[mi][ni][r] + bg[ni];
          const float p = ap_[mi][ni][r] + bp[ni];
          const float s = __builtin_amdgcn_rcpf(1.0f + __expf(-g));
          v[r] = mr[r] * s * p;
        }
        *(uint2*)(plane + (size_t)c * NPOS + m0 + pos0) =
            make_uint2(cvt_pk_bf16(v[0], v[1]), cvt_pk_bf16(v[2], v[3]));
      }
    }

    if (tt + 1 < NTILE) STAGE_WRITE(cb ^ 1);  // vmcnt waits land here
    __syncthreads();
  }
}

// ---------------------------------------------------------------- kernel B
// Per-channel GEMM out[c] = A_c * B_c^T, bf16 [512][512].
// 256x256 tile, BK=64, 8 waves (2Mx4N), double-buffered LDS (128 KB,
// 1 block/CU), counted-vmcnt pipeline, row-XOR swizzle (identical pattern
// to the validated 128² version: rows are 64 shorts, chunk ^= row&7).
__global__ __launch_bounds__(512) void tri_gemm(
    const unsigned short* __restrict__ a_ws,
    const unsigned short* __restrict__ b_ws,
    float* __restrict__ out) {
  __shared__ unsigned short sA[2][256 * 64];  // 64 KB
  __shared__ unsigned short sB[2][256 * 64];  // 64 KB

  const int t = threadIdx.x, lane = t & 63, wave = t >> 6;
  const int wm = wave >> 2;        // 0..1 -> 128-row band
  const int wn = wave & 3;         // 0..3 -> 64-col band

  const int L    = blockIdx.x;     // 0..511
  const int xcd  = L & 7;
  const int slot = L >> 3;         // 0..63
  const int c    = xcd * 16 + (slot >> 2);  // 16 channels per XCD
  const int tile = slot & 3;       // 4 tiles of channel c, schedule-adjacent
  const int ti   = tile >> 1, tj = tile & 1;
  const int i0 = ti * 256, j0 = tj * 256;

  const unsigned short* Ap = a_ws + (size_t)c * NPOS + (size_t)i0 * NDIM;
  const unsigned short* Bp = b_ws + (size_t)c * NPOS + (size_t)j0 * NDIM;

  f32x4 acc[8][4];
#pragma unroll
  for (int mi = 0; mi < 8; ++mi)
#pragma unroll
    for (int ni = 0; ni < 4; ++ni) acc[mi][ni] = (f32x4){0.f, 0.f, 0.f, 0.f};

  const int srow   = t >> 3;  // 0..63: row within a 64-row staging group
  const int schunk = t & 7;   // physical 16B chunk within 64-short row
  const int mrow = wm * 128 + (lane & 15);
  const int nrow = wn * 64 + (lane & 15);

  auto STAGE = [&](int b, int kk) {  // 8 global_load_lds per thread
    const int k0 = kk * 64;  // shorts
#pragma unroll
    for (int i = 0; i < 4; ++i) {
      const int row = i * 64 + srow;
      const int kcs = schunk ^ (row & 7);  // swizzled source chunk
      __builtin_amdgcn_global_load_lds(
          (const __attribute__((address_space(1))) unsigned int*)(Ap + (size_t)row * NDIM + k0 + kcs * 8),
          (__attribute__((address_space(3))) unsigned int*)&sA[b][(i * 512 + t) * 8], 16, 0, 0);
      __builtin_amdgcn_global_load_lds(
          (const __attribute__((address_space(1))) unsigned int*)(Bp + (size_t)row * NDIM + k0 + kcs * 8),
          (__attribute__((address_space(3))) unsigned int*)&sB[b][(i * 512 + t) * 8], 16, 0, 0);
    }
  };

  auto COMPUTE = [&](int cur) {
#pragma unroll
    for (int ksub = 0; ksub < 2; ++ksub) {
      const int kc = ksub * 4 + (lane >> 4);  // logical 16B chunk 0..7
      bf16x8 af[8], bfr[4];
#pragma unroll
      for (int mi = 0; mi < 8; ++mi) {
        const int r = mrow + mi * 16;
        af[mi] = *(const bf16x8*)&sA[cur][r * 64 + ((kc ^ (r & 7)) << 3)];
      }
#pragma unroll
      for (int ni = 0; ni < 4; ++ni) {
        const int r = nrow + ni * 16;
        bfr[ni] = *(const bf16x8*)&sB[cur][r * 64 + ((kc ^ (r & 7)) << 3)];
      }
#pragma unroll
      for (int mi = 0; mi < 8; ++mi)
#pragma unroll
        for (int ni = 0; ni < 4; ++ni)
          acc[mi][ni] = __builtin_amdgcn_mfma_f32_16x16x32_bf16(af[mi], bfr[ni], acc[mi][ni], 0, 0, 0);
    }
  };

  STAGE(0, 0);  // 8 loads in flight

#pragma unroll 1
  for (int kk = 0; kk < 7; ++kk) {
    const int cur = kk & 1;
    STAGE(cur ^ 1, kk + 1);                       // +8 loads (16 in flight)
    asm volatile("s_waitcnt vmcnt(8)" ::: "memory");  // kk's 8 complete
    __builtin_amdgcn_s_barrier();                 // buf[cur] visible to all
    COMPUTE(cur);
    __builtin_amdgcn_s_barrier();                 // all done reading buf[cur]
  }
  // peeled last K-step: drain remaining loads
  asm volatile("s_waitcnt vmcnt(0)" ::: "memory");
  __builtin_amdgcn_s_barrier();
  COMPUTE(1);

  float* O = out + (size_t)c * NPOS + (size_t)i0 * NDIM + j0;
#pragma unroll
  for (int mi = 0; mi < 8; ++mi)
#pragma unroll
    for (int r = 0; r < 4; ++r) {
      const int m = wm * 128 + mi * 16 + (lane >> 4) * 4 + r;
#pragma unroll
      for (int ni = 0; ni < 4; ++ni) {
        const int n = wn * 64 + ni * 16 + (lane & 15);
        O[(size_t)m * NDIM + n] = acc[mi][ni][r];
      }
    }
}

// ---------------------------------------------------------------- launcher
extern "C" void kernel_launch(void* const* d_in, const int* in_sizes, int n_in,
                              void* d_out, int out_size, void* d_ws, size_t ws_size,
                              hipStream_t stream) {
  const float* z    = (const float*)d_in[0];
  const float* mask = (const float*)d_in[1];
  const float* wag  = (const float*)d_in[2];
  const float* bag  = (const float*)d_in[3];
  const float* wap  = (const float*)d_in[4];
  const float* bap  = (const float*)d_in[5];
  const float* wbg  = (const float*)d_in[6];
  const float* bbg  = (const float*)d_in[7];
  const float* wbp  = (const float*)d_in[8];
  const float* bbp  = (const float*)d_in[9];
  float* out = (float*)d_out;

  unsigned short* wbf  = (unsigned short*)d_ws;
  unsigned short* a_ws = (unsigned short*)((char*)d_ws + 131072);
  unsigned short* b_ws = (unsigned short*)((char*)d_ws + 131072 + (size_t)CH * NPOS * 2);

  conv_weights<<<dim3(256), dim3(256), 0, stream>>>(wag, wap, wbg, wbp, wbf);
  proj_fuse<<<dim3(NPOS / POSB, 2), dim3(256), 0, stream>>>(
      z, mask, wbf, bag, bap, bbg, bbp, a_ws, b_ws);
  tri_gemm<<<dim3(512), dim3(512), 0, stream>>>(a_ws, b_ws, out);
}